// Round 1
// baseline (530.943 us; speedup 1.0000x reference)
//
#include <hip/hip_runtime.h>
#include <hip/hip_bf16.h>

#define DIM 1024
#define HEADS 16
#define DH 64
#define SEQ 2048
#define BATCH 4
#define ROWS (BATCH * SEQ)   // 8192
#define NQKV (3 * DIM)       // 3072

typedef __attribute__((ext_vector_type(8))) __bf16 bf16x8;
typedef __attribute__((ext_vector_type(4))) __bf16 bf16x4;
typedef __attribute__((ext_vector_type(4))) float f32x4;

__device__ inline void gload16(const void* g, void* l) {
  __builtin_amdgcn_global_load_lds(
      (const __attribute__((address_space(1))) void*)g,
      (__attribute__((address_space(3))) void*)l, 16, 0, 0);
}

// ---------------- LayerNorm + cast to bf16 ----------------
__global__ __launch_bounds__(256) void ln_kernel(
    const float* __restrict__ x, const float* __restrict__ gamma,
    const float* __restrict__ beta, __bf16* __restrict__ xnb) {
  const int row = blockIdx.x;
  const int tid = threadIdx.x;
  const float4* xr = (const float4*)(x + (size_t)row * DIM);
  float4 v = xr[tid];
  float s1 = v.x + v.y + v.z + v.w;
  float s2 = v.x * v.x + v.y * v.y + v.z * v.z + v.w * v.w;
#pragma unroll
  for (int d = 32; d > 0; d >>= 1) {
    s1 += __shfl_xor(s1, d);
    s2 += __shfl_xor(s2, d);
  }
  __shared__ float red1[4], red2[4];
  const int wave = tid >> 6, lane = tid & 63;
  if (lane == 0) { red1[wave] = s1; red2[wave] = s2; }
  __syncthreads();
  s1 = red1[0] + red1[1] + red1[2] + red1[3];
  s2 = red2[0] + red2[1] + red2[2] + red2[3];
  const float mean = s1 * (1.0f / DIM);
  const float var = s2 * (1.0f / DIM) - mean * mean;
  const float rstd = rsqrtf(var + 1e-5f);
  float4 g = ((const float4*)gamma)[tid];
  float4 b = ((const float4*)beta)[tid];
  bf16x4 o;
  o[0] = (__bf16)((v.x - mean) * rstd * g.x + b.x);
  o[1] = (__bf16)((v.y - mean) * rstd * g.y + b.y);
  o[2] = (__bf16)((v.z - mean) * rstd * g.z + b.z);
  o[3] = (__bf16)((v.w - mean) * rstd * g.w + b.w);
  *(bf16x4*)(xnb + (size_t)row * DIM + tid * 4) = o;
}

// ---------------- transpose + cast (K x N fp32 -> N x K bf16) ----------------
__global__ __launch_bounds__(256) void transpose_cast(
    const float* __restrict__ in, __bf16* __restrict__ outT, int rows, int cols) {
  __shared__ float tile[32][33];
  const int tx = threadIdx.x & 31, ty = threadIdx.x >> 5;  // ty 0..7
  const int c0 = blockIdx.x * 32, r0 = blockIdx.y * 32;
#pragma unroll
  for (int rr = ty; rr < 32; rr += 8)
    tile[rr][tx] = in[(size_t)(r0 + rr) * cols + c0 + tx];
  __syncthreads();
#pragma unroll
  for (int rr = ty; rr < 32; rr += 8)
    outT[(size_t)(c0 + rr) * rows + r0 + tx] = (__bf16)tile[tx][rr];
}

// ---------------- 128x128 MFMA GEMM, A (MxK) @ Bt (NxK), both bf16 ----------------
// MODE 0: write fp32 C to Cout (ld = N)
// MODE 1: QKV scatter: Q,K -> (b,h,seq,dh) bf16; V -> (b,h,dh,seq) bf16
template <int MODE>
__global__ __launch_bounds__(256) void gemm128(
    const __bf16* __restrict__ A, const __bf16* __restrict__ Bt, int K, int N,
    float* __restrict__ Cout, __bf16* __restrict__ qb, __bf16* __restrict__ kb,
    __bf16* __restrict__ vtb) {
  __shared__ __bf16 As[128 * 32];
  __shared__ __bf16 Bs[128 * 32];
  const int tid = threadIdx.x;
  const int wave = tid >> 6, lane = tid & 63;
  const int quad = lane >> 4, l16 = lane & 15;
  const int wm = wave >> 1, wn = wave & 1;
  const size_t tileM = (size_t)blockIdx.x * 128;
  const size_t tileN = (size_t)blockIdx.y * 128;

  f32x4 acc[4][4];
#pragma unroll
  for (int i = 0; i < 4; ++i)
#pragma unroll
    for (int j = 0; j < 4; ++j) acc[i][j] = (f32x4){0.f, 0.f, 0.f, 0.f};

  const int srow = lane >> 2;        // 0..15
  const int scol = (lane & 3) * 8;   // element offset in 32-wide k

  for (int k0 = 0; k0 < K; k0 += 32) {
    __syncthreads();
#pragma unroll
    for (int p = 0; p < 2; ++p) {
      const int rbase = p * 64 + wave * 16;
      gload16(A + (tileM + rbase + srow) * (size_t)K + k0 + scol, &As[rbase * 32]);
      gload16(Bt + (tileN + rbase + srow) * (size_t)K + k0 + scol, &Bs[rbase * 32]);
    }
    __syncthreads();
    bf16x8 af[4], bfr[4];
#pragma unroll
    for (int mt = 0; mt < 4; ++mt)
      af[mt] = *(const bf16x8*)&As[(wm * 64 + mt * 16 + l16) * 32 + quad * 8];
#pragma unroll
    for (int nt = 0; nt < 4; ++nt)
      bfr[nt] = *(const bf16x8*)&Bs[(wn * 64 + nt * 16 + l16) * 32 + quad * 8];
#pragma unroll
    for (int mt = 0; mt < 4; ++mt)
#pragma unroll
      for (int nt = 0; nt < 4; ++nt)
        acc[mt][nt] = __builtin_amdgcn_mfma_f32_16x16x32_bf16(af[mt], bfr[nt],
                                                              acc[mt][nt], 0, 0, 0);
  }

  if (MODE == 0) {
#pragma unroll
    for (int mt = 0; mt < 4; ++mt)
#pragma unroll
      for (int nt = 0; nt < 4; ++nt) {
        const size_t c = tileN + wn * 64 + nt * 16 + l16;
#pragma unroll
        for (int r = 0; r < 4; ++r) {
          const size_t m = tileM + wm * 64 + mt * 16 + quad * 4 + r;
          Cout[m * (size_t)N + c] = acc[mt][nt][r];
        }
      }
  } else {
    const int sel = (int)(tileN >> 10);  // 0=q 1=k 2=v (128-col tile never straddles)
    __bf16* dst = (sel == 0) ? qb : (sel == 1) ? kb : vtb;
#pragma unroll
    for (int mt = 0; mt < 4; ++mt)
#pragma unroll
      for (int nt = 0; nt < 4; ++nt) {
        const int c = (int)(tileN & 1023) + wn * 64 + nt * 16 + l16;
        const int head = c >> 6, dh = c & 63;
#pragma unroll
        for (int r = 0; r < 4; ++r) {
          const size_t m = tileM + wm * 64 + mt * 16 + quad * 4 + r;
          const int b = (int)(m >> 11), seq = (int)(m & 2047);
          const __bf16 val = (__bf16)acc[mt][nt][r];
          if (sel < 2)
            dst[(((size_t)b * HEADS + head) * SEQ + seq) * DH + dh] = val;
          else
            dst[(((size_t)b * HEADS + head) * DH + dh) * SEQ + seq] = val;
        }
      }
  }
}

// ---------------- flash-style causal attention ----------------
// grid: (SEQ/128, BATCH*HEADS); block 256 (4 waves, each owns 32 q-rows)
__global__ __launch_bounds__(256) void attn_kernel(
    const __bf16* __restrict__ qb, const __bf16* __restrict__ kb,
    const __bf16* __restrict__ vtb, __bf16* __restrict__ ob) {
  const int i = blockIdx.x;   // q tile
  const int bh = blockIdx.y;  // batch*heads
  const int tid = threadIdx.x;
  const int wave = tid >> 6, lane = tid & 63;
  const int quad = lane >> 4, l16 = lane & 15;

  __shared__ __bf16 Ks[128 * 64];
  __shared__ __bf16 Vs[64 * 128];
  __shared__ __bf16 Ps[4][32 * 128];

  // Q fragments, pre-scaled by dh^-0.5 = 0.125 (exact power of two in bf16)
  bf16x8 qf[2][2];
  {
    const __bf16* qbase = qb + ((size_t)bh * SEQ + (size_t)i * 128 + wave * 32) * DH;
#pragma unroll
    for (int mt = 0; mt < 2; ++mt)
#pragma unroll
      for (int ks = 0; ks < 2; ++ks) {
        bf16x8 v = *(const bf16x8*)(qbase + (mt * 16 + l16) * DH + ks * 32 + quad * 8);
#pragma unroll
        for (int e = 0; e < 8; ++e) v[e] = (__bf16)((float)v[e] * 0.125f);
        qf[mt][ks] = v;
      }
  }

  float m_i[2][4], l_i[2][4];
  f32x4 o_acc[2][4];
#pragma unroll
  for (int mt = 0; mt < 2; ++mt)
#pragma unroll
    for (int r = 0; r < 4; ++r) { m_i[mt][r] = -1e30f; l_i[mt][r] = 0.f; }
#pragma unroll
  for (int mt = 0; mt < 2; ++mt)
#pragma unroll
    for (int nv = 0; nv < 4; ++nv) o_acc[mt][nv] = (f32x4){0.f, 0.f, 0.f, 0.f};

  for (int j = 0; j <= i; ++j) {
    __syncthreads();  // all waves done reading Ks/Vs of previous iter
    {
      const __bf16* kgb = kb + ((size_t)bh * SEQ + (size_t)j * 128) * DH;
#pragma unroll
      for (int p = 0; p < 4; ++p) {
        const int rbase = p * 32 + wave * 8;
        gload16(kgb + (rbase + (lane >> 3)) * DH + (lane & 7) * 8, &Ks[rbase * DH]);
      }
      const __bf16* vgb = vtb + (size_t)bh * DH * SEQ + (size_t)j * 128;
#pragma unroll
      for (int p = 0; p < 4; ++p) {
        const int rbase = p * 16 + wave * 4;
        gload16(vgb + (rbase + (lane >> 4)) * (size_t)SEQ + (lane & 15) * 8,
                &Vs[rbase * 128]);
      }
    }
    __syncthreads();  // staging complete

    // S = Qs K^T  (wave's 32 rows x 128 cols)
    f32x4 sa[2][8];
#pragma unroll
    for (int mt = 0; mt < 2; ++mt)
#pragma unroll
      for (int nt = 0; nt < 8; ++nt) sa[mt][nt] = (f32x4){0.f, 0.f, 0.f, 0.f};
#pragma unroll
    for (int ks = 0; ks < 2; ++ks)
#pragma unroll
      for (int nt = 0; nt < 8; ++nt) {
        bf16x8 kf = *(const bf16x8*)&Ks[(nt * 16 + l16) * DH + ks * 32 + quad * 8];
#pragma unroll
        for (int mt = 0; mt < 2; ++mt)
          sa[mt][nt] =
              __builtin_amdgcn_mfma_f32_16x16x32_bf16(qf[mt][ks], kf, sa[mt][nt], 0, 0, 0);
      }

    if (j == i) {  // causal mask on the diagonal tile
#pragma unroll
      for (int mt = 0; mt < 2; ++mt)
#pragma unroll
        for (int nt = 0; nt < 8; ++nt) {
          const int col = nt * 16 + l16;
#pragma unroll
          for (int r = 0; r < 4; ++r) {
            const int row = wave * 32 + mt * 16 + quad * 4 + r;
            if (col > row) sa[mt][nt][r] = -1e30f;
          }
        }
    }

    // online softmax (rows live across the 16-lane group)
#pragma unroll
    for (int mt = 0; mt < 2; ++mt)
#pragma unroll
      for (int r = 0; r < 4; ++r) {
        float mx = sa[mt][0][r];
#pragma unroll
        for (int nt = 1; nt < 8; ++nt) mx = fmaxf(mx, sa[mt][nt][r]);
#pragma unroll
        for (int d = 1; d < 16; d <<= 1) mx = fmaxf(mx, __shfl_xor(mx, d));
        const float mnew = fmaxf(m_i[mt][r], mx);
        const float alpha = __expf(m_i[mt][r] - mnew);
        m_i[mt][r] = mnew;
        float rs = 0.f;
#pragma unroll
        for (int nt = 0; nt < 8; ++nt) {
          const float p = __expf(sa[mt][nt][r] - mnew);
          sa[mt][nt][r] = p;
          rs += p;
        }
#pragma unroll
        for (int d = 1; d < 16; d <<= 1) rs += __shfl_xor(rs, d);
        l_i[mt][r] = l_i[mt][r] * alpha + rs;
#pragma unroll
        for (int nv = 0; nv < 4; ++nv) o_acc[mt][nv][r] *= alpha;
      }

    // P (C-layout) -> LDS (row-major) for A-layout reads
#pragma unroll
    for (int mt = 0; mt < 2; ++mt)
#pragma unroll
      for (int nt = 0; nt < 8; ++nt)
#pragma unroll
        for (int r = 0; r < 4; ++r)
          Ps[wave][(mt * 16 + quad * 4 + r) * 128 + nt * 16 + l16] =
              (__bf16)sa[mt][nt][r];
    __syncthreads();  // P visible (also forces lgkmcnt drain)

    // O += P V
#pragma unroll
    for (int ks = 0; ks < 4; ++ks) {
      bf16x8 pf[2];
#pragma unroll
      for (int mt = 0; mt < 2; ++mt)
        pf[mt] = *(const bf16x8*)&Ps[wave][(mt * 16 + l16) * 128 + ks * 32 + quad * 8];
#pragma unroll
      for (int nv = 0; nv < 4; ++nv) {
        bf16x8 vf = *(const bf16x8*)&Vs[(nv * 16 + l16) * 128 + ks * 32 + quad * 8];
#pragma unroll
        for (int mt = 0; mt < 2; ++mt)
          o_acc[mt][nv] =
              __builtin_amdgcn_mfma_f32_16x16x32_bf16(pf[mt], vf, o_acc[mt][nv], 0, 0, 0);
      }
    }
  }

  // epilogue: O / l, write (b, seq, h*64+dh) bf16
  const int b = bh >> 4, h = bh & 15;
#pragma unroll
  for (int mt = 0; mt < 2; ++mt)
#pragma unroll
    for (int nv = 0; nv < 4; ++nv)
#pragma unroll
      for (int r = 0; r < 4; ++r) {
        const int seq = i * 128 + wave * 32 + mt * 16 + quad * 4 + r;
        const int col = h * DH + nv * 16 + l16;
        const float val = o_acc[mt][nv][r] / l_i[mt][r];
        ob[((size_t)b * SEQ + seq) * DIM + col] = (__bf16)val;
      }
}

// ---------------- launch ----------------
extern "C" void kernel_launch(void* const* d_in, const int* in_sizes, int n_in,
                              void* d_out, int out_size, void* d_ws, size_t ws_size,
                              hipStream_t stream) {
  const float* x = (const float*)d_in[0];
  const float* gamma = (const float*)d_in[1];
  const float* beta = (const float*)d_in[2];
  const float* w_qkv = (const float*)d_in[3];
  const float* w_out = (const float*)d_in[4];
  float* out = (float*)d_out;

  char* ws = (char*)d_ws;
  const size_t MB = 1024 * 1024;
  __bf16* xnb = (__bf16*)ws;                    // 16 MiB (dead after QKV gemm)
  __bf16* wqkvT = (__bf16*)(ws + 16 * MB);      // 6 MiB
  __bf16* woutT = (__bf16*)(ws + 24 * MB);      // 2 MiB
  __bf16* qbuf = (__bf16*)(ws + 32 * MB);       // 16 MiB
  __bf16* kbuf = (__bf16*)(ws + 48 * MB);       // 16 MiB
  __bf16* vtbuf = (__bf16*)(ws + 64 * MB);      // 16 MiB
  __bf16* attnb = xnb;                          // alias: xn dead by then

  ln_kernel<<<ROWS, 256, 0, stream>>>(x, gamma, beta, xnb);
  transpose_cast<<<dim3(NQKV / 32, DIM / 32), 256, 0, stream>>>(w_qkv, wqkvT, DIM, NQKV);
  transpose_cast<<<dim3(DIM / 32, DIM / 32), 256, 0, stream>>>(w_out, woutT, DIM, DIM);
  gemm128<1><<<dim3(ROWS / 128, NQKV / 128), 256, 0, stream>>>(
      xnb, wqkvT, DIM, NQKV, nullptr, qbuf, kbuf, vtbuf);
  attn_kernel<<<dim3(SEQ / 128, BATCH * HEADS), 256, 0, stream>>>(qbuf, kbuf, vtbuf, attnb);
  gemm128<0><<<dim3(ROWS / 128, DIM / 128), 256, 0, stream>>>(
      attnb, woutT, DIM, DIM, out, nullptr, nullptr, nullptr);
}

// Round 2
// 364.463 us; speedup vs baseline: 1.4568x; 1.4568x over previous
//
#include <hip/hip_runtime.h>
#include <hip/hip_bf16.h>

#define DIM 1024
#define HEADS 16
#define DH 64
#define SEQ 2048
#define BATCH 4
#define ROWS (BATCH * SEQ)   // 8192
#define NQKV (3 * DIM)       // 3072

typedef __attribute__((ext_vector_type(8))) __bf16 bf16x8;
typedef __attribute__((ext_vector_type(4))) __bf16 bf16x4;
typedef __attribute__((ext_vector_type(4))) float f32x4;

__device__ inline void gload16(const void* g, void* l) {
  __builtin_amdgcn_global_load_lds(
      (const __attribute__((address_space(1))) void*)g,
      (__attribute__((address_space(3))) void*)l, 16, 0, 0);
}

// ---------------- LayerNorm + cast to bf16 ----------------
__global__ __launch_bounds__(256) void ln_kernel(
    const float* __restrict__ x, const float* __restrict__ gamma,
    const float* __restrict__ beta, __bf16* __restrict__ xnb) {
  const int row = blockIdx.x;
  const int tid = threadIdx.x;
  const float4* xr = (const float4*)(x + (size_t)row * DIM);
  float4 v = xr[tid];
  float s1 = v.x + v.y + v.z + v.w;
  float s2 = v.x * v.x + v.y * v.y + v.z * v.z + v.w * v.w;
#pragma unroll
  for (int d = 32; d > 0; d >>= 1) {
    s1 += __shfl_xor(s1, d);
    s2 += __shfl_xor(s2, d);
  }
  __shared__ float red1[4], red2[4];
  const int wave = tid >> 6, lane = tid & 63;
  if (lane == 0) { red1[wave] = s1; red2[wave] = s2; }
  __syncthreads();
  s1 = red1[0] + red1[1] + red1[2] + red1[3];
  s2 = red2[0] + red2[1] + red2[2] + red2[3];
  const float mean = s1 * (1.0f / DIM);
  const float var = s2 * (1.0f / DIM) - mean * mean;
  const float rstd = rsqrtf(var + 1e-5f);
  float4 g = ((const float4*)gamma)[tid];
  float4 b = ((const float4*)beta)[tid];
  bf16x4 o;
  o[0] = (__bf16)((v.x - mean) * rstd * g.x + b.x);
  o[1] = (__bf16)((v.y - mean) * rstd * g.y + b.y);
  o[2] = (__bf16)((v.z - mean) * rstd * g.z + b.z);
  o[3] = (__bf16)((v.w - mean) * rstd * g.w + b.w);
  *(bf16x4*)(xnb + (size_t)row * DIM + tid * 4) = o;
}

// ---------------- transpose + cast (K x N fp32 -> N x K bf16) ----------------
__global__ __launch_bounds__(256) void transpose_cast(
    const float* __restrict__ in, __bf16* __restrict__ outT, int rows, int cols) {
  __shared__ float tile[32][33];
  const int tx = threadIdx.x & 31, ty = threadIdx.x >> 5;  // ty 0..7
  const int c0 = blockIdx.x * 32, r0 = blockIdx.y * 32;
#pragma unroll
  for (int rr = ty; rr < 32; rr += 8)
    tile[rr][tx] = in[(size_t)(r0 + rr) * cols + c0 + tx];
  __syncthreads();
#pragma unroll
  for (int rr = ty; rr < 32; rr += 8)
    outT[(size_t)(c0 + rr) * rows + r0 + tx] = (__bf16)tile[tx][rr];
}

// ---------------- 128x128 MFMA GEMM, A (MxK) @ Bt (NxK), both bf16 ----------------
// LDS layout: As/Bs rows of 4 16B-chunks, chunk c holds global chunk c ^ ((row>>1)&3)
// -> frag reads are conflict-free (octet spans 8 distinct bank-groups).
// MODE 0: write fp32 C to Cout (ld = N)
// MODE 1: QKV scatter: Q,K -> (b,h,seq,dh) bf16; V -> (b,h,dh,seq) bf16 via LDS transpose
template <int MODE>
__global__ __launch_bounds__(256) void gemm128(
    const __bf16* __restrict__ A, const __bf16* __restrict__ Bt, int K, int N,
    float* __restrict__ Cout, __bf16* __restrict__ qb, __bf16* __restrict__ kb,
    __bf16* __restrict__ vtb) {
  __shared__ __bf16 smem[64 * 136];  // 8704 el: staging (8192) or V-transpose (8704)
  __bf16* As = smem;
  __bf16* Bs = smem + 4096;
  const int tid = threadIdx.x;
  const int wave = tid >> 6, lane = tid & 63;
  const int quad = lane >> 4, l16 = lane & 15;
  const int wm = wave >> 1, wn = wave & 1;
  const size_t tileM = (size_t)blockIdx.x * 128;
  const size_t tileN = (size_t)blockIdx.y * 128;

  f32x4 acc[4][4];
#pragma unroll
  for (int i = 0; i < 4; ++i)
#pragma unroll
    for (int j = 0; j < 4; ++j) acc[i][j] = (f32x4){0.f, 0.f, 0.f, 0.f};

  const int sr = lane >> 2;   // 0..15 row within 16-row group
  const int sc = lane & 3;    // chunk 0..3
  const int ck = (l16 >> 1) & 3;  // read-side swizzle key

  for (int k0 = 0; k0 < K; k0 += 32) {
    __syncthreads();
#pragma unroll
    for (int p = 0; p < 2; ++p) {
      const int rbase = p * 64 + wave * 16;
      const int row = rbase + sr;
      const int gc = (sc ^ ((row >> 1) & 3)) << 3;
      gload16(A + (tileM + row) * (size_t)K + k0 + gc, &As[rbase * 32]);
      gload16(Bt + (tileN + row) * (size_t)K + k0 + gc, &Bs[rbase * 32]);
    }
    __syncthreads();
    bf16x8 af[4], bfr[4];
#pragma unroll
    for (int mt = 0; mt < 4; ++mt)
      af[mt] = *(const bf16x8*)&As[(wm * 64 + mt * 16 + l16) * 32 + ((quad ^ ck) << 3)];
#pragma unroll
    for (int nt = 0; nt < 4; ++nt)
      bfr[nt] = *(const bf16x8*)&Bs[(wn * 64 + nt * 16 + l16) * 32 + ((quad ^ ck) << 3)];
#pragma unroll
    for (int mt = 0; mt < 4; ++mt)
#pragma unroll
      for (int nt = 0; nt < 4; ++nt)
        acc[mt][nt] = __builtin_amdgcn_mfma_f32_16x16x32_bf16(af[mt], bfr[nt],
                                                              acc[mt][nt], 0, 0, 0);
  }

  if (MODE == 0) {
#pragma unroll
    for (int mt = 0; mt < 4; ++mt)
#pragma unroll
      for (int nt = 0; nt < 4; ++nt) {
        const size_t c = tileN + wn * 64 + nt * 16 + l16;
#pragma unroll
        for (int r = 0; r < 4; ++r) {
          const size_t m = tileM + wm * 64 + mt * 16 + quad * 4 + r;
          Cout[m * (size_t)N + c] = acc[mt][nt][r];
        }
      }
  } else {
    const int sel = (int)(tileN >> 10);  // 0=q 1=k 2=v
    if (sel < 2) {
      __bf16* dst = (sel == 0) ? qb : kb;
#pragma unroll
      for (int mt = 0; mt < 4; ++mt)
#pragma unroll
        for (int nt = 0; nt < 4; ++nt) {
          const int c = (int)(tileN & 1023) + wn * 64 + nt * 16 + l16;
          const int head = c >> 6, dh = c & 63;
#pragma unroll
          for (int r = 0; r < 4; ++r) {
            const size_t m = tileM + wm * 64 + mt * 16 + quad * 4 + r;
            const int b = (int)(m >> 11), seq = (int)(m & 2047);
            dst[(((size_t)b * HEADS + head) * SEQ + seq) * DH + dh] =
                (__bf16)acc[mt][nt][r];
          }
        }
    } else {
      // V: transpose 128x128 tile through LDS in two 64-col passes -> coalesced
      const int b = (int)(tileM >> 11);
      const int seq0 = (int)(tileM & 2047);
      const int headbase = (int)((tileN & 1023) >> 6);
#pragma unroll
      for (int h = 0; h < 2; ++h) {
        __syncthreads();
        if (wn == h) {
#pragma unroll
          for (int mt = 0; mt < 4; ++mt)
#pragma unroll
            for (int nt = 0; nt < 4; ++nt)
#pragma unroll
              for (int r = 0; r < 4; ++r)
                smem[(nt * 16 + l16) * 136 + wm * 64 + mt * 16 + quad * 4 + r] =
                    (__bf16)acc[mt][nt][r];
        }
        __syncthreads();
        const int rr = tid >> 2;         // dh row 0..63
        const int m0 = (tid & 3) * 32;   // seq chunk
        __bf16* dst = vtb + (((size_t)b * HEADS + headbase + h) * DH + rr) * SEQ +
                      seq0 + m0;
#pragma unroll
        for (int q = 0; q < 4; ++q)
          *(bf16x8*)(dst + q * 8) = *(const bf16x8*)&smem[rr * 136 + m0 + q * 8];
      }
    }
  }
}

// ---------------- flash-style causal attention, balanced + double-buffered ----------
// grid: (8, BATCH*HEADS). Block x handles q-tiles i and 15-i -> exactly 17 kv-iters.
// K/V staged with XOR chunk swizzle (conflict-free frag reads); Ps chunked 32 cols.
__global__ __launch_bounds__(256) void attn_kernel(
    const __bf16* __restrict__ qb, const __bf16* __restrict__ kb,
    const __bf16* __restrict__ vtb, __bf16* __restrict__ ob) {
  const int bx = blockIdx.x;  // 0..7
  const int bh = blockIdx.y;
  const int tid = threadIdx.x;
  const int wave = tid >> 6, lane = tid & 63;
  const int quad = lane >> 4, l16 = lane & 15;

  __shared__ __bf16 Ks[2][128 * 64];
  __shared__ __bf16 Vs[2][64 * 128];
  __shared__ __bf16 Ps[4][32 * 40];

  const __bf16* kg = kb + (size_t)bh * SEQ * DH;
  const __bf16* vg = vtb + (size_t)bh * DH * SEQ;

  const int i1 = bx, i2 = 15 - bx;
  const int T = 17;

  const int kr = lane >> 3, kc = lane & 7;   // K stage: 8 rows x 8 chunks
  const int vr = lane >> 4, vc = lane & 15;  // V stage: 4 rows x 16 chunks

  auto stage = [&](int buf, int j) {
#pragma unroll
    for (int p = 0; p < 4; ++p) {
      const int rbase = p * 32 + wave * 8;
      const int row = rbase + kr;
      gload16(kg + (size_t)(j * 128 + row) * DH + ((kc ^ (row & 7)) << 3),
              &Ks[buf][rbase * 64]);
    }
#pragma unroll
    for (int p = 0; p < 4; ++p) {
      const int rbase = p * 16 + wave * 4;
      const int row = rbase + vr;
      gload16(vg + (size_t)row * SEQ + j * 128 + ((vc ^ (row & 7)) << 3),
              &Vs[buf][rbase * 128]);
    }
  };

  bf16x8 qf[2][2];
  auto load_q = [&](int i) {
    const __bf16* qbase = qb + ((size_t)bh * SEQ + (size_t)i * 128 + wave * 32) * DH;
#pragma unroll
    for (int mt = 0; mt < 2; ++mt)
#pragma unroll
      for (int ks = 0; ks < 2; ++ks) {
        bf16x8 v = *(const bf16x8*)(qbase + (mt * 16 + l16) * DH + ks * 32 + quad * 8);
#pragma unroll
        for (int e = 0; e < 8; ++e) v[e] = (__bf16)((float)v[e] * 0.125f);
        qf[mt][ks] = v;
      }
  };

  float m_i[2][4], l_i[2][4];
  f32x4 o_acc[2][4];
  auto reset_state = [&]() {
#pragma unroll
    for (int mt = 0; mt < 2; ++mt)
#pragma unroll
      for (int r = 0; r < 4; ++r) { m_i[mt][r] = -1e30f; l_i[mt][r] = 0.f; }
#pragma unroll
    for (int mt = 0; mt < 2; ++mt)
#pragma unroll
      for (int nv = 0; nv < 4; ++nv) o_acc[mt][nv] = (f32x4){0.f, 0.f, 0.f, 0.f};
  };
  const int b_out = bh >> 4, h_out = bh & 15;
  auto epilogue = [&](int i) {
#pragma unroll
    for (int mt = 0; mt < 2; ++mt)
#pragma unroll
      for (int nv = 0; nv < 4; ++nv)
#pragma unroll
        for (int r = 0; r < 4; ++r) {
          const int seq = i * 128 + wave * 32 + mt * 16 + quad * 4 + r;
          const int col = h_out * DH + nv * 16 + l16;
          ob[((size_t)b_out * SEQ + seq) * DIM + col] =
              (__bf16)(o_acc[mt][nv][r] / l_i[mt][r]);
        }
  };

  load_q(i1);
  reset_state();
  stage(0, 0);

  for (int t = 0; t < T; ++t) {
    __syncthreads();  // staging for t complete; prev-iter reads of this buf done
    if (t + 1 < T) {
      const int jn = (t + 1 <= bx) ? (t + 1) : (t - bx);
      stage((t + 1) & 1, jn);
    }
    const int buf = t & 1;
    const int i = (t <= bx) ? i1 : i2;
    const int j = (t <= bx) ? t : (t - bx - 1);
    const bool diag = (j == i);

    // S = Q K^T : wave's 32 q-rows x 128 kv
    f32x4 sa[2][8];
#pragma unroll
    for (int mt = 0; mt < 2; ++mt)
#pragma unroll
      for (int nt = 0; nt < 8; ++nt) sa[mt][nt] = (f32x4){0.f, 0.f, 0.f, 0.f};
#pragma unroll
    for (int nt = 0; nt < 8; ++nt)
#pragma unroll
      for (int ks = 0; ks < 2; ++ks) {
        bf16x8 kf = *(const bf16x8*)&Ks[buf][(nt * 16 + l16) * 64 +
                                            (((ks * 4 + quad) ^ (l16 & 7)) << 3)];
#pragma unroll
        for (int mt = 0; mt < 2; ++mt)
          sa[mt][nt] =
              __builtin_amdgcn_mfma_f32_16x16x32_bf16(qf[mt][ks], kf, sa[mt][nt], 0, 0, 0);
      }

    if (diag) {
#pragma unroll
      for (int mt = 0; mt < 2; ++mt)
#pragma unroll
        for (int nt = 0; nt < 8; ++nt) {
          const int col = nt * 16 + l16;
#pragma unroll
          for (int r = 0; r < 4; ++r) {
            const int row = wave * 32 + mt * 16 + quad * 4 + r;
            if (col > row) sa[mt][nt][r] = -1e30f;
          }
        }
    }

    // online softmax (row lives across the 16-lane group)
#pragma unroll
    for (int mt = 0; mt < 2; ++mt)
#pragma unroll
      for (int r = 0; r < 4; ++r) {
        float mx = sa[mt][0][r];
#pragma unroll
        for (int nt = 1; nt < 8; ++nt) mx = fmaxf(mx, sa[mt][nt][r]);
#pragma unroll
        for (int d = 1; d < 16; d <<= 1) mx = fmaxf(mx, __shfl_xor(mx, d));
        const float mnew = fmaxf(m_i[mt][r], mx);
        const float alpha = __expf(m_i[mt][r] - mnew);
        m_i[mt][r] = mnew;
        float rs = 0.f;
#pragma unroll
        for (int nt = 0; nt < 8; ++nt) {
          const float p = __expf(sa[mt][nt][r] - mnew);
          sa[mt][nt][r] = p;
          rs += p;
        }
#pragma unroll
        for (int d = 1; d < 16; d <<= 1) rs += __shfl_xor(rs, d);
        l_i[mt][r] = l_i[mt][r] * alpha + rs;
#pragma unroll
        for (int nv = 0; nv < 4; ++nv) o_acc[mt][nv][r] *= alpha;
      }

    // O += P V in 4 chunks of 32 kv; Ps is wave-private (no barrier needed)
#pragma unroll
    for (int c = 0; c < 4; ++c) {
#pragma unroll
      for (int mt = 0; mt < 2; ++mt)
#pragma unroll
        for (int ntl = 0; ntl < 2; ++ntl) {
          const int nt = c * 2 + ntl;
#pragma unroll
          for (int r = 0; r < 4; ++r)
            Ps[wave][(mt * 16 + quad * 4 + r) * 40 + ntl * 16 + l16] =
                (__bf16)sa[mt][nt][r];
        }
      bf16x8 pf[2];
#pragma unroll
      for (int mt = 0; mt < 2; ++mt)
        pf[mt] = *(const bf16x8*)&Ps[wave][(mt * 16 + l16) * 40 + quad * 8];
#pragma unroll
      for (int nv = 0; nv < 4; ++nv) {
        bf16x8 vf = *(const bf16x8*)&Vs[buf][(nv * 16 + l16) * 128 +
                                            (((c * 4 + quad) ^ (l16 & 7)) << 3)];
#pragma unroll
        for (int mt = 0; mt < 2; ++mt)
          o_acc[mt][nv] =
              __builtin_amdgcn_mfma_f32_16x16x32_bf16(pf[mt], vf, o_acc[mt][nv], 0, 0, 0);
      }
    }

    if (t == bx) {  // phase 0 done: flush, switch to q-tile i2
      epilogue(i1);
      reset_state();
      load_q(i2);
    }
  }
  epilogue(i2);
}

// ---------------- launch ----------------
extern "C" void kernel_launch(void* const* d_in, const int* in_sizes, int n_in,
                              void* d_out, int out_size, void* d_ws, size_t ws_size,
                              hipStream_t stream) {
  const float* x = (const float*)d_in[0];
  const float* gamma = (const float*)d_in[1];
  const float* beta = (const float*)d_in[2];
  const float* w_qkv = (const float*)d_in[3];
  const float* w_out = (const float*)d_in[4];
  float* out = (float*)d_out;

  char* ws = (char*)d_ws;
  const size_t MB = 1024 * 1024;
  __bf16* xnb = (__bf16*)ws;                    // 16 MiB (dead after QKV gemm)
  __bf16* wqkvT = (__bf16*)(ws + 16 * MB);      // 6 MiB
  __bf16* woutT = (__bf16*)(ws + 24 * MB);      // 2 MiB
  __bf16* qbuf = (__bf16*)(ws + 32 * MB);       // 16 MiB
  __bf16* kbuf = (__bf16*)(ws + 48 * MB);       // 16 MiB
  __bf16* vtbuf = (__bf16*)(ws + 64 * MB);      // 16 MiB
  __bf16* attnb = xnb;                          // alias: xn dead by then

  ln_kernel<<<ROWS, 256, 0, stream>>>(x, gamma, beta, xnb);
  transpose_cast<<<dim3(NQKV / 32, DIM / 32), 256, 0, stream>>>(w_qkv, wqkvT, DIM, NQKV);
  transpose_cast<<<dim3(DIM / 32, DIM / 32), 256, 0, stream>>>(w_out, woutT, DIM, DIM);
  gemm128<1><<<dim3(ROWS / 128, NQKV / 128), 256, 0, stream>>>(
      xnb, wqkvT, DIM, NQKV, nullptr, qbuf, kbuf, vtbuf);
  attn_kernel<<<dim3(8, BATCH * HEADS), 256, 0, stream>>>(qbuf, kbuf, vtbuf, attnb);
  gemm128<0><<<dim3(ROWS / 128, DIM / 128), 256, 0, stream>>>(
      attnb, woutT, DIM, DIM, out, nullptr, nullptr, nullptr);
}

// Round 4
// 320.621 us; speedup vs baseline: 1.6560x; 1.1367x over previous
//
#include <hip/hip_runtime.h>
#include <hip/hip_bf16.h>

#define DIM 1024
#define HEADS 16
#define DH 64
#define SEQ 2048
#define BATCH 4
#define ROWS (BATCH * SEQ)   // 8192
#define NQKV (3 * DIM)       // 3072

typedef __attribute__((ext_vector_type(8))) __bf16 bf16x8;
typedef __attribute__((ext_vector_type(4))) __bf16 bf16x4;
typedef __attribute__((ext_vector_type(4))) float f32x4;

__device__ inline void gload16(const void* g, void* l) {
  __builtin_amdgcn_global_load_lds(
      (const __attribute__((address_space(1))) void*)g,
      (__attribute__((address_space(3))) void*)l, 16, 0, 0);
}

// ---------------- LayerNorm + cast to bf16 ----------------
__global__ __launch_bounds__(256) void ln_kernel(
    const float* __restrict__ x, const float* __restrict__ gamma,
    const float* __restrict__ beta, __bf16* __restrict__ xnb) {
  const int row = blockIdx.x;
  const int tid = threadIdx.x;
  const float4* xr = (const float4*)(x + (size_t)row * DIM);
  float4 v = xr[tid];
  float s1 = v.x + v.y + v.z + v.w;
  float s2 = v.x * v.x + v.y * v.y + v.z * v.z + v.w * v.w;
#pragma unroll
  for (int d = 32; d > 0; d >>= 1) {
    s1 += __shfl_xor(s1, d);
    s2 += __shfl_xor(s2, d);
  }
  __shared__ float red1[4], red2[4];
  const int wave = tid >> 6, lane = tid & 63;
  if (lane == 0) { red1[wave] = s1; red2[wave] = s2; }
  __syncthreads();
  s1 = red1[0] + red1[1] + red1[2] + red1[3];
  s2 = red2[0] + red2[1] + red2[2] + red2[3];
  const float mean = s1 * (1.0f / DIM);
  const float var = s2 * (1.0f / DIM) - mean * mean;
  const float rstd = rsqrtf(var + 1e-5f);
  float4 g = ((const float4*)gamma)[tid];
  float4 b = ((const float4*)beta)[tid];
  bf16x4 o;
  o[0] = (__bf16)((v.x - mean) * rstd * g.x + b.x);
  o[1] = (__bf16)((v.y - mean) * rstd * g.y + b.y);
  o[2] = (__bf16)((v.z - mean) * rstd * g.z + b.z);
  o[3] = (__bf16)((v.w - mean) * rstd * g.w + b.w);
  *(bf16x4*)(xnb + (size_t)row * DIM + tid * 4) = o;
}

// ---------------- transpose + cast (K x N fp32 -> N x K bf16) ----------------
__global__ __launch_bounds__(256) void transpose_cast(
    const float* __restrict__ in, __bf16* __restrict__ outT, int rows, int cols) {
  __shared__ float tile[32][33];
  const int tx = threadIdx.x & 31, ty = threadIdx.x >> 5;  // ty 0..7
  const int c0 = blockIdx.x * 32, r0 = blockIdx.y * 32;
#pragma unroll
  for (int rr = ty; rr < 32; rr += 8)
    tile[rr][tx] = in[(size_t)(r0 + rr) * cols + c0 + tx];
  __syncthreads();
#pragma unroll
  for (int rr = ty; rr < 32; rr += 8)
    outT[(size_t)(c0 + rr) * rows + r0 + tx] = (__bf16)tile[tx][rr];
}

// ---------------- 128x128 MFMA GEMM, A (MxK) @ Bt (NxK), both bf16 ----------------
// LDS layout: As/Bs rows of 4 16B-chunks, chunk c holds global chunk c ^ ((row>>1)&3)
// MODE 0: write fp32 C to Cout (ld = N)
// MODE 1: QKV scatter: Q,K -> (b,h,seq,dh) bf16; V -> (b,h,dh,seq) bf16 via LDS transpose
template <int MODE>
__global__ __launch_bounds__(256) void gemm128(
    const __bf16* __restrict__ A, const __bf16* __restrict__ Bt, int K, int N,
    float* __restrict__ Cout, __bf16* __restrict__ qb, __bf16* __restrict__ kb,
    __bf16* __restrict__ vtb) {
  __shared__ __bf16 smem[64 * 136];  // staging (8192) or V-transpose (8704)
  __bf16* As = smem;
  __bf16* Bs = smem + 4096;
  const int tid = threadIdx.x;
  const int wave = tid >> 6, lane = tid & 63;
  const int quad = lane >> 4, l16 = lane & 15;
  const int wm = wave >> 1, wn = wave & 1;
  const size_t tileM = (size_t)blockIdx.x * 128;
  const size_t tileN = (size_t)blockIdx.y * 128;

  f32x4 acc[4][4];
#pragma unroll
  for (int i = 0; i < 4; ++i)
#pragma unroll
    for (int j = 0; j < 4; ++j) acc[i][j] = (f32x4){0.f, 0.f, 0.f, 0.f};

  const int sr = lane >> 2;   // 0..15 row within 16-row group
  const int sc = lane & 3;    // chunk 0..3
  const int ck = (l16 >> 1) & 3;  // read-side swizzle key

  for (int k0 = 0; k0 < K; k0 += 32) {
    __syncthreads();
#pragma unroll
    for (int p = 0; p < 2; ++p) {
      const int rbase = p * 64 + wave * 16;
      const int row = rbase + sr;
      const int gc = (sc ^ ((row >> 1) & 3)) << 3;
      gload16(A + (tileM + row) * (size_t)K + k0 + gc, &As[rbase * 32]);
      gload16(Bt + (tileN + row) * (size_t)K + k0 + gc, &Bs[rbase * 32]);
    }
    __syncthreads();
    bf16x8 af[4], bfr[4];
#pragma unroll
    for (int mt = 0; mt < 4; ++mt)
      af[mt] = *(const bf16x8*)&As[(wm * 64 + mt * 16 + l16) * 32 + ((quad ^ ck) << 3)];
#pragma unroll
    for (int nt = 0; nt < 4; ++nt)
      bfr[nt] = *(const bf16x8*)&Bs[(wn * 64 + nt * 16 + l16) * 32 + ((quad ^ ck) << 3)];
#pragma unroll
    for (int mt = 0; mt < 4; ++mt)
#pragma unroll
      for (int nt = 0; nt < 4; ++nt)
        acc[mt][nt] = __builtin_amdgcn_mfma_f32_16x16x32_bf16(af[mt], bfr[nt],
                                                              acc[mt][nt], 0, 0, 0);
  }

  if (MODE == 0) {
#pragma unroll
    for (int mt = 0; mt < 4; ++mt)
#pragma unroll
      for (int nt = 0; nt < 4; ++nt) {
        const size_t c = tileN + wn * 64 + nt * 16 + l16;
#pragma unroll
        for (int r = 0; r < 4; ++r) {
          const size_t m = tileM + wm * 64 + mt * 16 + quad * 4 + r;
          Cout[m * (size_t)N + c] = acc[mt][nt][r];
        }
      }
  } else {
    const int sel = (int)(tileN >> 10);  // 0=q 1=k 2=v
    if (sel < 2) {
      __bf16* dst = (sel == 0) ? qb : kb;
#pragma unroll
      for (int mt = 0; mt < 4; ++mt)
#pragma unroll
        for (int nt = 0; nt < 4; ++nt) {
          const int c = (int)(tileN & 1023) + wn * 64 + nt * 16 + l16;
          const int head = c >> 6, dh = c & 63;
#pragma unroll
          for (int r = 0; r < 4; ++r) {
            const size_t m = tileM + wm * 64 + mt * 16 + quad * 4 + r;
            const int b = (int)(m >> 11), seq = (int)(m & 2047);
            dst[(((size_t)b * HEADS + head) * SEQ + seq) * DH + dh] =
                (__bf16)acc[mt][nt][r];
          }
        }
    } else {
      // V: transpose 128x128 tile through LDS in two 64-col passes -> coalesced
      const int b = (int)(tileM >> 11);
      const int seq0 = (int)(tileM & 2047);
      const int headbase = (int)((tileN & 1023) >> 6);
#pragma unroll
      for (int h = 0; h < 2; ++h) {
        __syncthreads();
        if (wn == h) {
#pragma unroll
          for (int mt = 0; mt < 4; ++mt)
#pragma unroll
            for (int nt = 0; nt < 4; ++nt)
#pragma unroll
              for (int r = 0; r < 4; ++r)
                smem[(nt * 16 + l16) * 136 + wm * 64 + mt * 16 + quad * 4 + r] =
                    (__bf16)acc[mt][nt][r];
        }
        __syncthreads();
        const int rr = tid >> 2;         // dh row 0..63
        const int m0 = (tid & 3) * 32;   // seq chunk
        __bf16* dst = vtb + (((size_t)b * HEADS + headbase + h) * DH + rr) * SEQ +
                      seq0 + m0;
#pragma unroll
        for (int q = 0; q < 4; ++q)
          *(bf16x8*)(dst + q * 8) = *(const bf16x8*)&smem[rr * 136 + m0 + q * 8];
      }
    }
  }
}

// ---------------- flash-style causal attention (S^T formulation) ----------------
// grid: (8, BATCH*HEADS). Block x handles q-tiles bx and 15-bx -> exactly 17 kv-iters.
// S^T = K·Q^T: C-layout col=l16=q-row -> softmax rows are lane-local (2 shfl steps),
// P^T packs 4 consecutive kv/lane -> b64 LDS writes; O^T = V^T·P^T -> alpha/l lane-local,
// epilogue packs 4 consecutive dh -> b64 global stores.
__global__ __launch_bounds__(256) void attn_kernel(
    const __bf16* __restrict__ qb, const __bf16* __restrict__ kb,
    const __bf16* __restrict__ vtb, __bf16* __restrict__ ob) {
  const int bx = blockIdx.x;  // 0..7
  const int bh = blockIdx.y;
  const int tid = threadIdx.x;
  const int wave = tid >> 6, lane = tid & 63;
  const int quad = lane >> 4, l16 = lane & 15;

  __shared__ __bf16 Ks[2][128 * 64];
  __shared__ __bf16 Vs[2][64 * 128];
  __shared__ __bf16 Ps[4][32 * 36];  // per-wave P^T chunk: 32 qrows x 32 kv (+4 pad)

  const __bf16* kg = kb + (size_t)bh * SEQ * DH;
  const __bf16* vg = vtb + (size_t)bh * DH * SEQ;

  const int i1 = bx, i2 = 15 - bx;
  const int T = 17;

  const int kr = lane >> 3, kc = lane & 7;   // K stage: 8 rows x 8 chunks
  const int vr = lane >> 4, vc = lane & 15;  // V stage: 4 rows x 16 chunks

  auto stage = [&](int buf, int j) {
#pragma unroll
    for (int p = 0; p < 4; ++p) {
      const int rbase = p * 32 + wave * 8;
      const int row = rbase + kr;
      gload16(kg + (size_t)(j * 128 + row) * DH + ((kc ^ (row & 7)) << 3),
              &Ks[buf][rbase * 64]);
    }
#pragma unroll
    for (int p = 0; p < 4; ++p) {
      const int rbase = p * 16 + wave * 4;
      const int row = rbase + vr;
      gload16(vg + (size_t)row * SEQ + j * 128 + ((vc ^ (row & 7)) << 3),
              &Vs[buf][rbase * 128]);
    }
  };

  // Q as B-operand fragments, pre-scaled by dh^-0.5 * log2(e) (exp2 domain)
  const float QSCALE = 0.125f * 1.44269504088896f;
  bf16x8 qf[2][2];
  auto load_q = [&](int i) {
    const __bf16* qbase = qb + ((size_t)bh * SEQ + (size_t)i * 128 + wave * 32) * DH;
#pragma unroll
    for (int mt = 0; mt < 2; ++mt)
#pragma unroll
      for (int ks = 0; ks < 2; ++ks) {
        bf16x8 v = *(const bf16x8*)(qbase + (mt * 16 + l16) * DH + ks * 32 + quad * 8);
#pragma unroll
        for (int e = 0; e < 8; ++e) v[e] = (__bf16)((float)v[e] * QSCALE);
        qf[mt][ks] = v;
      }
  };

  float m_i[2], l_i[2];      // per-lane: q-rows mt*16+l16 (+wave*32)
  f32x4 o_acc[4][2];         // O^T: [md dh-frag][mt q-frag], col=l16=qrow
  auto reset_state = [&]() {
#pragma unroll
    for (int mt = 0; mt < 2; ++mt) { m_i[mt] = -1e30f; l_i[mt] = 0.f; }
#pragma unroll
    for (int md = 0; md < 4; ++md)
#pragma unroll
      for (int mt = 0; mt < 2; ++mt) o_acc[md][mt] = (f32x4){0.f, 0.f, 0.f, 0.f};
  };
  const int b_out = bh >> 4, h_out = bh & 15;
  auto epilogue = [&](int i) {
#pragma unroll
    for (int mt = 0; mt < 2; ++mt) {
      const float inv = __builtin_amdgcn_rcpf(l_i[mt]);
      const int seq = i * 128 + wave * 32 + mt * 16 + l16;
      __bf16* dst = ob + ((size_t)b_out * SEQ + seq) * DIM + h_out * DH;
#pragma unroll
      for (int md = 0; md < 4; ++md) {
        bf16x4 pk;
#pragma unroll
        for (int r = 0; r < 4; ++r) pk[r] = (__bf16)(o_acc[md][mt][r] * inv);
        *(bf16x4*)(dst + md * 16 + quad * 4) = pk;
      }
    }
  };

  load_q(i1);
  reset_state();
  stage(0, 0);

  for (int t = 0; t < T; ++t) {
    __syncthreads();  // staging for t complete; prev-iter reads of this buf done
    if (t + 1 < T) {
      const int jn = (t + 1 <= bx) ? (t + 1) : (t - bx);
      stage((t + 1) & 1, jn);
    }
    const int buf = t & 1;
    const int i = (t <= bx) ? i1 : i2;
    const int j = (t <= bx) ? t : (t - bx - 1);
    const bool diag = (j == i);

    // S^T = K Q^T : rows(quad*4+r)=kv, cols(l16)=q-row
    f32x4 sa[8][2];
#pragma unroll
    for (int nt = 0; nt < 8; ++nt)
#pragma unroll
      for (int mt = 0; mt < 2; ++mt) sa[nt][mt] = (f32x4){0.f, 0.f, 0.f, 0.f};
#pragma unroll
    for (int nt = 0; nt < 8; ++nt)
#pragma unroll
      for (int ks = 0; ks < 2; ++ks) {
        bf16x8 kf = *(const bf16x8*)&Ks[buf][(nt * 16 + l16) * 64 +
                                            (((ks * 4 + quad) ^ (l16 & 7)) << 3)];
#pragma unroll
        for (int mt = 0; mt < 2; ++mt)
          sa[nt][mt] =
              __builtin_amdgcn_mfma_f32_16x16x32_bf16(kf, qf[mt][ks], sa[nt][mt], 0, 0, 0);
      }

    if (diag) {
#pragma unroll
      for (int nt = 0; nt < 8; ++nt)
#pragma unroll
        for (int mt = 0; mt < 2; ++mt) {
          const int qrow = wave * 32 + mt * 16 + l16;
#pragma unroll
          for (int r = 0; r < 4; ++r) {
            const int kv = nt * 16 + quad * 4 + r;
            if (kv > qrow) sa[nt][mt][r] = -1e30f;
          }
        }
    }

    // online softmax: each lane owns 2 full rows (32 kv values each + 2 shfl steps)
    float alpha[2];
#pragma unroll
    for (int mt = 0; mt < 2; ++mt) {
      float mx = -1e30f;
#pragma unroll
      for (int nt = 0; nt < 8; ++nt)
#pragma unroll
        for (int r = 0; r < 4; ++r) mx = fmaxf(mx, sa[nt][mt][r]);
      mx = fmaxf(mx, __shfl_xor(mx, 16));
      mx = fmaxf(mx, __shfl_xor(mx, 32));
      const float mnew = fmaxf(m_i[mt], mx);
      alpha[mt] = exp2f(m_i[mt] - mnew);
      m_i[mt] = mnew;
      float rs = 0.f;
#pragma unroll
      for (int nt = 0; nt < 8; ++nt)
#pragma unroll
        for (int r = 0; r < 4; ++r) {
          const float p = exp2f(sa[nt][mt][r] - mnew);
          sa[nt][mt][r] = p;
          rs += p;
        }
      rs += __shfl_xor(rs, 16);
      rs += __shfl_xor(rs, 32);
      l_i[mt] = l_i[mt] * alpha[mt] + rs;
    }
#pragma unroll
    for (int md = 0; md < 4; ++md)
#pragma unroll
      for (int mt = 0; mt < 2; ++mt)
#pragma unroll
        for (int r = 0; r < 4; ++r) o_acc[md][mt][r] *= alpha[mt];

    // O^T += V^T P^T in 4 chunks of 32 kv; Ps wave-private (no barrier)
#pragma unroll
    for (int c = 0; c < 4; ++c) {
#pragma unroll
      for (int mt = 0; mt < 2; ++mt)
#pragma unroll
        for (int ntl = 0; ntl < 2; ++ntl) {
          const int nt = c * 2 + ntl;
          bf16x4 pk;
#pragma unroll
          for (int r = 0; r < 4; ++r) pk[r] = (__bf16)sa[nt][mt][r];
          *(bf16x4*)&Ps[wave][(mt * 16 + l16) * 36 + ntl * 16 + quad * 4] = pk;
        }
      bf16x8 pf[2];
#pragma unroll
      for (int mt = 0; mt < 2; ++mt)
        pf[mt] = *(const bf16x8*)&Ps[wave][(mt * 16 + l16) * 36 + quad * 8];
#pragma unroll
      for (int md = 0; md < 4; ++md) {
        bf16x8 vf = *(const bf16x8*)&Vs[buf][(md * 16 + l16) * 128 +
                                            (((c * 4 + quad) ^ (l16 & 7)) << 3)];
#pragma unroll
        for (int mt = 0; mt < 2; ++mt)
          o_acc[md][mt] =
              __builtin_amdgcn_mfma_f32_16x16x32_bf16(vf, pf[mt], o_acc[md][mt], 0, 0, 0);
      }
    }

    if (t == bx) {  // phase 0 done: flush, switch to q-tile i2
      epilogue(i1);
      reset_state();
      load_q(i2);
    }
  }
  epilogue(i2);
}

// ---------------- launch ----------------
extern "C" void kernel_launch(void* const* d_in, const int* in_sizes, int n_in,
                              void* d_out, int out_size, void* d_ws, size_t ws_size,
                              hipStream_t stream) {
  const float* x = (const float*)d_in[0];
  const float* gamma = (const float*)d_in[1];
  const float* beta = (const float*)d_in[2];
  const float* w_qkv = (const float*)d_in[3];
  const float* w_out = (const float*)d_in[4];
  float* out = (float*)d_out;

  char* ws = (char*)d_ws;
  const size_t MB = 1024 * 1024;
  __bf16* xnb = (__bf16*)ws;                    // 16 MiB (dead after QKV gemm)
  __bf16* wqkvT = (__bf16*)(ws + 16 * MB);      // 6 MiB
  __bf16* woutT = (__bf16*)(ws + 24 * MB);      // 2 MiB
  __bf16* qbuf = (__bf16*)(ws + 32 * MB);       // 16 MiB
  __bf16* kbuf = (__bf16*)(ws + 48 * MB);       // 16 MiB
  __bf16* vtbuf = (__bf16*)(ws + 64 * MB);      // 16 MiB
  __bf16* attnb = xnb;                          // alias: xn dead by then

  ln_kernel<<<ROWS, 256, 0, stream>>>(x, gamma, beta, xnb);
  transpose_cast<<<dim3(NQKV / 32, DIM / 32), 256, 0, stream>>>(w_qkv, wqkvT, DIM, NQKV);
  transpose_cast<<<dim3(DIM / 32, DIM / 32), 256, 0, stream>>>(w_out, woutT, DIM, DIM);
  gemm128<1><<<dim3(ROWS / 128, NQKV / 128), 256, 0, stream>>>(
      xnb, wqkvT, DIM, NQKV, nullptr, qbuf, kbuf, vtbuf);
  attn_kernel<<<dim3(8, BATCH * HEADS), 256, 0, stream>>>(qbuf, kbuf, vtbuf, attnb);
  gemm128<0><<<dim3(ROWS / 128, DIM / 128), 256, 0, stream>>>(
      attnb, woutT, DIM, DIM, out, nullptr, nullptr, nullptr);
}